// Round 4
// baseline (352.801 us; speedup 1.0000x reference)
//
#include <hip/hip_runtime.h>

// ---------------------------------------------------------------------------
// AdversarialHead, fully fused single-pass kernel.
//
//   h[m,140]    = cf[m,:] @ W1[0:512,:] + W1[512+s0] + W1[512+s1] + W1[512+s2] + b1
//   pred[m,256] = h[m,:] @ W2 + b2
//   L[m,18]     = cf[m,:] @ Wc[0:512,:] + nf[m,:] @ Wc[512:1024,:]  (bias=0)
//   a*(f,a,j)   = softmax over a (32 agents/frame);  m = f*32+a, M = 65536
//
// Round-6 (resubmitted -- round-3 bench was an infra failure, no signal).
// Changes vs round-5 (158 us, neutral -- post-mortem found the WCP frag loads
// were issued AFTER the stream loads and consumed in-section, so every acc3
// wait retired the freshly-issued stream prefetch: the pipeline never
// existed):
//  * WCP frags preloaded at section TOP, before the stream loads. The acc3
//    MFMA wait is now vmcnt(4) (4 younger stream loads) and never drains the
//    stream queue -> streams genuinely live 2 sections (~600+ cy).
//  * 1-deep pipeline on the 9 W1P frags via two NAMED register sets (fa/fb):
//    section s consumes set P (issued one full section earlier, age >= L2
//    latency) and prefetches set Q for s+1. No runtime indexing -> no scratch.
//  * Issue order per section (sched_barrier pinned):
//      [cvt] [9 W1P -> Q] [4 WCP cur] | [4 stream (youngest)] | [MFMAs]
// ---------------------------------------------------------------------------

using bf16x8  = __attribute__((ext_vector_type(8))) __bf16;
using floatx4 = __attribute__((ext_vector_type(4))) float;

__device__ __forceinline__ unsigned short f2bf(float f) {
    unsigned int u = __float_as_uint(f);
    return (unsigned short)((u + 0x7fffu + ((u >> 16) & 1u)) >> 16);
}
__device__ __forceinline__ bf16x8 cvt8r(float4 x, float4 y) {
    union { bf16x8 v; unsigned short s[8]; } u;
    u.s[0] = f2bf(x.x); u.s[1] = f2bf(x.y); u.s[2] = f2bf(x.z); u.s[3] = f2bf(x.w);
    u.s[4] = f2bf(y.x); u.s[5] = f2bf(y.y); u.s[6] = f2bf(y.z); u.s[7] = f2bf(y.w);
    return u.v;
}

// prepacked ws offsets (bf16 elements)
#define OFF_W1P 0                        // [16][9][64][8]   gemm1 B-frags
#define OFF_W2P (OFF_W1P + 16*9*512)     // [5][16][64][8]   gemm2 B-frags
#define OFF_WCP (OFF_W2P + 5*16*512)     // [32][2][64][8]   inv   B-frags

// d_out element offsets (fp32)
#define OFF_A0 ((size_t)16777216)
#define OFF_A1 ((size_t)17301504)
#define OFF_A2 ((size_t)17694720)

// ---------------------------------------------------------------------------
// Prepack weights fp32 -> bf16 in B-fragment order.
// frag elem: lane l holds B[n*16 + (l&15)][kc*32 + (l>>4)*8 + e], e=0..7.
__global__ __launch_bounds__(256) void prep_kernel(
    const float* __restrict__ W1,   // [530][140]
    const float* __restrict__ W2,   // [140][256]
    const float* __restrict__ Wi0,  // [1024][8]
    const float* __restrict__ Wi1,  // [1024][6]
    const float* __restrict__ Wi2,  // [1024][4]
    unsigned short* __restrict__ ws)
{
    const int T1 = 16*9*512;           // 73728
    const int T2 = T1 + 5*16*512;      // 114688
    const int total = T2 + 32*2*512;   // 147456
    for (int idx = blockIdx.x * 256 + threadIdx.x; idx < total; idx += gridDim.x * 256) {
        unsigned short v = 0;
        if (idx < T1) {                               // W1P
            int e = idx & 7, l = (idx >> 3) & 63;
            int n = (idx >> 9) % 9, kc = idx / (9*512);
            int k = kc*32 + ((l >> 4) << 3) + e, j = n*16 + (l & 15);
            if (j < 140) v = f2bf(W1[k*140 + j]);
            ws[OFF_W1P + idx] = v;
        } else if (idx < T2) {                        // W2P (K padded 140->160)
            int i2 = idx - T1;
            int e = i2 & 7, l = (i2 >> 3) & 63;
            int n = (i2 >> 9) & 15, kc = i2 >> 13;
            int k = kc*32 + ((l >> 4) << 3) + e, j = n*16 + (l & 15);
            if (k < 140) v = f2bf(W2[k*256 + j]);
            ws[OFF_W2P + i2] = v;
        } else {                                      // WcP: heads concat (8|6|4)
            int i3 = idx - T2;
            int e = i3 & 7, l = (i3 >> 3) & 63;
            int n = (i3 >> 9) & 1, kc = i3 >> 10;
            int k = kc*32 + ((l >> 4) << 3) + e, j = n*16 + (l & 15);
            if (j < 8)       v = f2bf(Wi0[k*8 + j]);
            else if (j < 14) v = f2bf(Wi1[k*6 + (j - 8)]);
            else if (j < 18) v = f2bf(Wi2[k*4 + (j - 14)]);
            ws[OFF_WCP + i3] = v;
        }
    }
}

#define MFMA16(av, bv, acc) __builtin_amdgcn_mfma_f32_16x16x32_bf16(av, bv, acc, 0, 0, 0)

// One merged K-section. Consumes W1P frag set P (loaded one section earlier),
// prefetches set Q for chunk KN (if PREF). WCP frags for the CURRENT chunk are
// loaded at section top (before the stream loads!) so their wait is vmcnt(4)
// and never drains the stream queue. Stream chunk KP prefetched (if PRES) as
// the youngest vmem ops.
#define SECTION(X0, X1, Y0, Y1, P, Q, KC, KN, KP, PREF, PRES) do {             \
    bf16x8 avc = cvt8r(X0, X1);                                                \
    bf16x8 avn = cvt8r(Y0, Y1);                                                \
    if (PREF) {                                                                \
        const unsigned short* bq = W1P + (size_t)((KN) * 9) * 512 + lo8;       \
        Q##0 = *(const bf16x8*)(bq);                                           \
        Q##1 = *(const bf16x8*)(bq + 512);                                     \
        Q##2 = *(const bf16x8*)(bq + 1024);                                    \
        Q##3 = *(const bf16x8*)(bq + 1536);                                    \
        Q##4 = *(const bf16x8*)(bq + 2048);                                    \
        Q##5 = *(const bf16x8*)(bq + 2560);                                    \
        Q##6 = *(const bf16x8*)(bq + 3072);                                    \
        Q##7 = *(const bf16x8*)(bq + 3584);                                    \
        Q##8 = *(const bf16x8*)(bq + 4096);                                    \
    }                                                                          \
    const unsigned short* cpc = WCP + (size_t)((KC) * 2) * 512 + lo8;          \
    const unsigned short* cpn = WCP + (size_t)((16 + (KC)) * 2) * 512 + lo8;   \
    bf16x8 wc0 = *(const bf16x8*)(cpc);                                        \
    bf16x8 wc1 = *(const bf16x8*)(cpc + 512);                                  \
    bf16x8 wc2 = *(const bf16x8*)(cpn);                                        \
    bf16x8 wc3 = *(const bf16x8*)(cpn + 512);                                  \
    __builtin_amdgcn_sched_barrier(0);                                         \
    if (PRES) {                                                                \
        X0 = *(const float4*)(cfr + (KP) * 32);                                \
        X1 = *(const float4*)(cfr + (KP) * 32 + 4);                            \
        Y0 = *(const float4*)(nfr + (KP) * 32);                                \
        Y1 = *(const float4*)(nfr + (KP) * 32 + 4);                            \
        __builtin_amdgcn_sched_barrier(0);                                     \
    }                                                                          \
    acc1[0] = MFMA16(avc, P##0, acc1[0]);                                      \
    acc1[1] = MFMA16(avc, P##1, acc1[1]);                                      \
    acc1[2] = MFMA16(avc, P##2, acc1[2]);                                      \
    acc1[3] = MFMA16(avc, P##3, acc1[3]);                                      \
    acc1[4] = MFMA16(avc, P##4, acc1[4]);                                      \
    acc1[5] = MFMA16(avc, P##5, acc1[5]);                                      \
    acc1[6] = MFMA16(avc, P##6, acc1[6]);                                      \
    acc1[7] = MFMA16(avc, P##7, acc1[7]);                                      \
    acc1[8] = MFMA16(avc, P##8, acc1[8]);                                      \
    acc3[0] = MFMA16(avc, wc0, acc3[0]);                                       \
    acc3[1] = MFMA16(avc, wc1, acc3[1]);                                       \
    acc3[0] = MFMA16(avn, wc2, acc3[0]);                                       \
    acc3[1] = MFMA16(avn, wc3, acc3[1]);                                       \
} while (0)

// ---------------------------------------------------------------------------
__global__ __launch_bounds__(256) void fused_kernel(
    const float* __restrict__ cf,
    const float* __restrict__ nf,
    const int* __restrict__ actions,   // [2048][3][32]
    const float* __restrict__ W1,      // rows 512..529: one-hot add rows
    const float* __restrict__ b1,
    const float* __restrict__ b2,
    const unsigned short* __restrict__ ws,
    float* __restrict__ outp)
{
    __shared__ alignas(16) __bf16 hs[64 * 168];   // h tile, stride 168 (2-way banks)
    __shared__ float Us[18 * 144];                // one-hot rows of W1 (fp32)
    __shared__ float b1s[144];
    __shared__ float b2s[256];
    __shared__ float Ls[64 * 20];                 // inv logits
    __shared__ float rmx[36], rsc[36];
    __shared__ int   sidx[192];

    const int t = threadIdx.x, w = t >> 6, l = t & 63;
    const int m0 = blockIdx.x * 64;
    const int q = l >> 4, col = l & 15;
    const int lo8 = l * 8;
    const unsigned short* W1P = ws + OFF_W1P;
    const unsigned short* W2P = ws + OFF_W2P;
    const unsigned short* WCP = ws + OFF_WCP;

    // ---- stage constants: hoist loads into regs (all in flight), then LDS
    {
        float uv[11];
#pragma unroll
        for (int it = 0; it < 11; ++it) {
            int i = t + it * 256;
            uv[it] = 0.f;
            if (i < 18 * 144) {
                int s = i / 144, j = i - s * 144;
                if (j < 140) uv[it] = W1[(512 + s) * 140 + j];
            }
        }
        float bv1 = (t < 140) ? b1[t] : 0.f;
        float bv2 = b2[t];
        int sv = 0;
        if (t < 192) {
            int r = t / 3, tt = t - r * 3;
            int m = m0 + r;
            int start = (tt == 0) ? 0 : (tt == 1 ? 8 : 14);
            sv = actions[(m >> 5) * 96 + tt * 32 + (m & 31)] + start;
        }
#pragma unroll
        for (int it = 0; it < 11; ++it) {
            int i = t + it * 256;
            if (i < 18 * 144) Us[i] = uv[it];
        }
        if (t < 144) b1s[t] = bv1;
        b2s[t] = bv2;
        if (t < 192) sidx[t] = sv;
    }

    // A-frag source row for this lane (A layout: row = lane&15, k = quad*8+j)
    const float* cfr = cf + (size_t)(m0 + w * 16 + col) * 512 + q * 8;
    const float* nfr = nf + (size_t)(m0 + w * 16 + col) * 512 + q * 8;

    floatx4 acc1[9], acc3[2];
#pragma unroll
    for (int n = 0; n < 9; ++n) { acc1[n][0]=0.f; acc1[n][1]=0.f; acc1[n][2]=0.f; acc1[n][3]=0.f; }
#pragma unroll
    for (int n = 0; n < 2; ++n) { acc3[n][0]=0.f; acc3[n][1]=0.f; acc3[n][2]=0.f; acc3[n][3]=0.f; }

    const int base = blockIdx.x & 15;   // K-phase rotation (channel spread)

    // ---- merged stream loop: 16 sections; streams 2-deep, W1P frags 1-deep
    {
        bf16x8 fa0, fa1, fa2, fa3, fa4, fa5, fa6, fa7, fa8;
        bf16x8 fb0, fb1, fb2, fb3, fb4, fb5, fb6, fb7, fb8;

        // prologue: frag set A for section 0 (issued BEFORE streams so the
        // streams stay youngest in the vmcnt queue)
        {
            const unsigned short* bq = W1P + (size_t)(base * 9) * 512 + lo8;
            fa0 = *(const bf16x8*)(bq);
            fa1 = *(const bf16x8*)(bq + 512);
            fa2 = *(const bf16x8*)(bq + 1024);
            fa3 = *(const bf16x8*)(bq + 1536);
            fa4 = *(const bf16x8*)(bq + 2048);
            fa5 = *(const bf16x8*)(bq + 2560);
            fa6 = *(const bf16x8*)(bq + 3072);
            fa7 = *(const bf16x8*)(bq + 3584);
            fa8 = *(const bf16x8*)(bq + 4096);
        }
        __builtin_amdgcn_sched_barrier(0);
        const int kA = base, kB = (base + 1) & 15;
        float4 xa0 = *(const float4*)(cfr + kA * 32);
        float4 xa1 = *(const float4*)(cfr + kA * 32 + 4);
        float4 ya0 = *(const float4*)(nfr + kA * 32);
        float4 ya1 = *(const float4*)(nfr + kA * 32 + 4);
        float4 xb0 = *(const float4*)(cfr + kB * 32);
        float4 xb1 = *(const float4*)(cfr + kB * 32 + 4);
        float4 yb0 = *(const float4*)(nfr + kB * 32);
        float4 yb1 = *(const float4*)(nfr + kB * 32 + 4);
        __builtin_amdgcn_sched_barrier(0);

        for (int i = 0; i < 14; i += 2) {
            SECTION(xa0, xa1, ya0, ya1, fa, fb,
                    ((base + i)     & 15), ((base + i + 1) & 15), ((base + i + 2) & 15), 1, 1);
            SECTION(xb0, xb1, yb0, yb1, fb, fa,
                    ((base + i + 1) & 15), ((base + i + 2) & 15), ((base + i + 3) & 15), 1, 1);
        }
        // tail: section 14 still prefetches frags for section 15; no stream
        // prefetch (chunks base+16/17 don't exist). Section 15: no prefetch.
        SECTION(xa0, xa1, ya0, ya1, fa, fb, ((base + 14) & 15), ((base + 15) & 15), 0, 1, 0);
        SECTION(xb0, xb1, yb0, yb1, fb, fa, ((base + 15) & 15), 0, 0, 0, 0);
    }

    __syncthreads();   // Us/b1s/sidx staged -> readable

    // ---- epilogue 1: h = acc1 + b1 + one-hot rows; write bf16 to LDS
    // C/D layout: col = lane&15, row = quad*4 + i
    const int r0 = w * 16 + (q << 2);
#pragma unroll
    for (int i = 0; i < 4; ++i) {
        int rr = r0 + i;
        int s0 = sidx[rr * 3], s1 = sidx[rr * 3 + 1], s2 = sidx[rr * 3 + 2];
#pragma unroll
        for (int n = 0; n < 9; ++n) {
            int j = n * 16 + col;
            float v = acc1[n][i] + b1s[j] + Us[s0 * 144 + j] + Us[s1 * 144 + j] + Us[s2 * 144 + j];
            ((unsigned short*)hs)[rr * 168 + j] = f2bf(v);
        }
    }
    {   // zero pad cols 144..159 (phase-2 K reads zeros there)
        int rr = t >> 2, g = t & 3;
        ushort4 z; z.x = z.y = z.z = z.w = 0;
        *(ushort4*)((unsigned short*)hs + rr * 168 + 144 + g * 4) = z;
    }
    // inv logits -> LDS (frees acc3 before phase 2)
#pragma unroll
    for (int n = 0; n < 2; ++n) {
        int j = n * 16 + col;
        if (j < 18) {
#pragma unroll
            for (int i = 0; i < 4; ++i) Ls[(r0 + i) * 20 + j] = acc3[n][i];
        }
    }
    __syncthreads();

    // ---- phase 2: pred = h @ W2 + b2 (K=160, 5 chunks), store fp32
    floatx4 acc2[16];
#pragma unroll
    for (int n = 0; n < 16; ++n) { acc2[n][0]=0.f; acc2[n][1]=0.f; acc2[n][2]=0.f; acc2[n][3]=0.f; }

    for (int kc = 0; kc < 5; ++kc) {
        bf16x8 av = *(const bf16x8*)&hs[(w * 16 + col) * 168 + kc * 32 + q * 8];
        const unsigned short* bp = W2P + (size_t)(kc * 16) * 512 + lo8;
#pragma unroll
        for (int n = 0; n < 16; ++n)
            acc2[n] = __builtin_amdgcn_mfma_f32_16x16x32_bf16(
                av, *(const bf16x8*)(bp + n * 512), acc2[n], 0, 0, 0);
    }
#pragma unroll
    for (int n = 0; n < 16; ++n) {
        int j = n * 16 + col;
        float bj = b2s[j];
#pragma unroll
        for (int i = 0; i < 4; ++i)
            outp[(size_t)(m0 + r0 + i) * 256 + j] = acc2[n][i] + bj;
    }

    // ---- phase 3: softmax over 32 agents per frame
    if (t < 36) {
        int fr = t / 18, j = t - fr * 18;
        float mx = -1e30f;
        for (int a = 0; a < 32; ++a) mx = fmaxf(mx, Ls[(fr * 32 + a) * 20 + j]);
        float s = 0.f;
        for (int a = 0; a < 32; ++a) s += expf(Ls[(fr * 32 + a) * 20 + j] - mx);
        rmx[t] = mx; rsc[t] = 1.f / s;
    }
    __syncthreads();

#pragma unroll
    for (int it = 0; it < 5; ++it) {               // 64*18 = 1152 outputs
        int idx = t + it * 256;
        if (idx < 1152) {
            int r = idx / 18, j = idx - r * 18;
            int fr = r >> 5;
            float v = expf(Ls[r * 20 + j] - rmx[fr * 18 + j]) * rsc[fr * 18 + j];
            int m = m0 + r;
            size_t o;
            if (j < 8)       o = OFF_A0 + (size_t)m * 8 + j;
            else if (j < 14) o = OFF_A1 + (size_t)m * 6 + (j - 8);
            else             o = OFF_A2 + (size_t)m * 4 + (j - 14);
            outp[o] = v;
        }
    }
}

// ---------------------------------------------------------------------------
extern "C" void kernel_launch(void* const* d_in, const int* in_sizes, int n_in,
                              void* d_out, int out_size, void* d_ws, size_t ws_size,
                              hipStream_t stream)
{
    const float* cf  = (const float*)d_in[0];
    const float* nf  = (const float*)d_in[1];
    const int*   act = (const int*)d_in[2];
    const float* W1  = (const float*)d_in[3];
    const float* b1  = (const float*)d_in[4];
    const float* W2  = (const float*)d_in[5];
    const float* b2  = (const float*)d_in[6];
    const float* Wi0 = (const float*)d_in[7];
    const float* Wi1 = (const float*)d_in[9];
    const float* Wi2 = (const float*)d_in[11];

    unsigned short* ws = (unsigned short*)d_ws;
    float* outp = (float*)d_out;

    hipLaunchKernelGGL(prep_kernel, dim3(144), dim3(256), 0, stream,
                       W1, W2, Wi0, Wi1, Wi2, ws);
    hipLaunchKernelGGL(fused_kernel, dim3(1024), dim3(256), 0, stream,
                       cf, nf, act, W1, b1, b2, ws, outp);
}

// Round 7
// 343.389 us; speedup vs baseline: 1.0274x; 1.0274x over previous
//
#include <hip/hip_runtime.h>

// ---------------------------------------------------------------------------
// AdversarialHead, fully fused single-pass kernel.
//
//   h[m,140]    = cf[m,:] @ W1[0:512,:] + W1[512+s0] + W1[512+s1] + W1[512+s2] + b1
//   pred[m,256] = h[m,:] @ W2 + b2
//   L[m,18]     = cf[m,:] @ Wc[0:512,:] + nf[m,:] @ Wc[512:1024,:]  (bias=0)
//   a*(f,a,j)   = softmax over a (32 agents/frame);  m = f*32+a, M = 65536
//
// Round-8 (de-risked round-7): rounds 5/6 both died with container failures
// on the first kernel using global_load_lds + raw s_barrier + manual vmcnt.
// This variant tests the SAME structural theory (move frag state out of
// registers -> higher occupancy -> more bytes in flight) using ONLY
// constructs proven to run in this harness (rounds 2/4):
//  * Weight frags staged per-block into a SINGLE 13KB LDS buffer via
//    reg-staging (global->reg->ds_write_b128), classic 2-barrier K-loop:
//    [ds_write frags(i)] [stage loads i+1] | barrier | [compute] | barrier.
//    Frees ~120 VGPRs of frag state vs round-6.
//  * Streams (cf/nf): 1-ahead prefetch, ping-pong named float4 sets.
//    __syncthreads drains vmcnt anyway, so depth-1 is the correct depth.
//  * LDS: frag buffer unioned with hs (post-loop) -> total ~39.6 KB ->
//    4 blocks/CU possible = grid-capped 16 waves/CU (vs measured ~8).
//  * Phase 2 split into 2 halves of 8 n-tiles (acc2: 64 -> 32 AGPR).
// ---------------------------------------------------------------------------

using bf16x8  = __attribute__((ext_vector_type(8))) __bf16;
using floatx4 = __attribute__((ext_vector_type(4))) float;

__device__ __forceinline__ unsigned short f2bf(float f) {
    unsigned int u = __float_as_uint(f);
    return (unsigned short)((u + 0x7fffu + ((u >> 16) & 1u)) >> 16);
}
__device__ __forceinline__ bf16x8 cvt8r(float4 x, float4 y) {
    union { bf16x8 v; unsigned short s[8]; } u;
    u.s[0] = f2bf(x.x); u.s[1] = f2bf(x.y); u.s[2] = f2bf(x.z); u.s[3] = f2bf(x.w);
    u.s[4] = f2bf(y.x); u.s[5] = f2bf(y.y); u.s[6] = f2bf(y.z); u.s[7] = f2bf(y.w);
    return u.v;
}

// prepacked ws offsets (bf16 elements)
#define OFF_W1P 0                        // [16][9][64][8]   gemm1 B-frags
#define OFF_W2P (OFF_W1P + 16*9*512)     // [5][16][64][8]   gemm2 B-frags
#define OFF_WCP (OFF_W2P + 5*16*512)     // [32][2][64][8]   inv   B-frags

// d_out element offsets (fp32)
#define OFF_A0 ((size_t)16777216)
#define OFF_A1 ((size_t)17301504)
#define OFF_A2 ((size_t)17694720)

// ---------------------------------------------------------------------------
// Prepack weights fp32 -> bf16 in B-fragment order.
// frag elem: lane l holds B[n*16 + (l&15)][kc*32 + (l>>4)*8 + e], e=0..7.
__global__ __launch_bounds__(256) void prep_kernel(
    const float* __restrict__ W1,   // [530][140]
    const float* __restrict__ W2,   // [140][256]
    const float* __restrict__ Wi0,  // [1024][8]
    const float* __restrict__ Wi1,  // [1024][6]
    const float* __restrict__ Wi2,  // [1024][4]
    unsigned short* __restrict__ ws)
{
    const int T1 = 16*9*512;           // 73728
    const int T2 = T1 + 5*16*512;      // 114688
    const int total = T2 + 32*2*512;   // 147456
    for (int idx = blockIdx.x * 256 + threadIdx.x; idx < total; idx += gridDim.x * 256) {
        unsigned short v = 0;
        if (idx < T1) {                               // W1P
            int e = idx & 7, l = (idx >> 3) & 63;
            int n = (idx >> 9) % 9, kc = idx / (9*512);
            int k = kc*32 + ((l >> 4) << 3) + e, j = n*16 + (l & 15);
            if (j < 140) v = f2bf(W1[k*140 + j]);
            ws[OFF_W1P + idx] = v;
        } else if (idx < T2) {                        // W2P (K padded 140->160)
            int i2 = idx - T1;
            int e = i2 & 7, l = (i2 >> 3) & 63;
            int n = (i2 >> 9) & 15, kc = i2 >> 13;
            int k = kc*32 + ((l >> 4) << 3) + e, j = n*16 + (l & 15);
            if (k < 140) v = f2bf(W2[k*256 + j]);
            ws[OFF_W2P + i2] = v;
        } else {                                      // WcP: heads concat (8|6|4)
            int i3 = idx - T2;
            int e = i3 & 7, l = (i3 >> 3) & 63;
            int n = (i3 >> 9) & 1, kc = i3 >> 10;
            int k = kc*32 + ((l >> 4) << 3) + e, j = n*16 + (l & 15);
            if (j < 8)       v = f2bf(Wi0[k*8 + j]);
            else if (j < 14) v = f2bf(Wi1[k*6 + (j - 8)]);
            else if (j < 18) v = f2bf(Wi2[k*4 + (j - 14)]);
            ws[OFF_WCP + i3] = v;
        }
    }
}

#define MFMA16(av, bv, acc) __builtin_amdgcn_mfma_f32_16x16x32_bf16(av, bv, acc, 0, 0, 0)

// ---------------------------------------------------------------------------
__global__ __launch_bounds__(256) void fused_kernel(
    const float* __restrict__ cf,
    const float* __restrict__ nf,
    const int* __restrict__ actions,   // [2048][3][32]
    const float* __restrict__ W1,      // rows 512..529: one-hot add rows
    const float* __restrict__ b1,
    const float* __restrict__ b2,
    const unsigned short* __restrict__ ws,
    float* __restrict__ outp)
{
    // frag staging (13 slots x 1024 B = 13312 B) UNION hs (64x168x2 = 21504 B)
    __shared__ alignas(16) unsigned short fragbuf[64 * 168];
    __shared__ float Us[18 * 144];                // one-hot rows of W1 (fp32)
    __shared__ float b1s[144];
    __shared__ float b2s[256];
    __shared__ float Ls[64 * 20];                 // inv logits
    __shared__ float rmx[36], rsc[36];
    __shared__ int   sidx[192];

    const int t = threadIdx.x, w = t >> 6, l = t & 63;
    const int m0 = blockIdx.x * 64;
    const int q = l >> 4, col = l & 15;
    const int lo8 = l * 8;
    const unsigned short* W1P = ws + OFF_W1P;
    const unsigned short* W2P = ws + OFF_W2P;
    const unsigned short* WCP = ws + OFF_WCP;

    // ---- stage constants: hoist loads into regs (all in flight), then LDS
    {
        float uv[11];
#pragma unroll
        for (int it = 0; it < 11; ++it) {
            int i = t + it * 256;
            uv[it] = 0.f;
            if (i < 18 * 144) {
                int s = i / 144, j = i - s * 144;
                if (j < 140) uv[it] = W1[(512 + s) * 140 + j];
            }
        }
        float bv1 = (t < 140) ? b1[t] : 0.f;
        float bv2 = b2[t];
        int sv = 0;
        if (t < 192) {
            int r = t / 3, tt = t - r * 3;
            int m = m0 + r;
            int start = (tt == 0) ? 0 : (tt == 1 ? 8 : 14);
            sv = actions[(m >> 5) * 96 + tt * 32 + (m & 31)] + start;
        }
#pragma unroll
        for (int it = 0; it < 11; ++it) {
            int i = t + it * 256;
            if (i < 18 * 144) Us[i] = uv[it];
        }
        if (t < 144) b1s[t] = bv1;
        b2s[t] = bv2;
        if (t < 192) sidx[t] = sv;
    }

    // A-frag source row for this lane (A layout: row = lane&15, k = quad*8+j)
    const float* cfr = cf + (size_t)(m0 + w * 16 + col) * 512 + q * 8;
    const float* nfr = nf + (size_t)(m0 + w * 16 + col) * 512 + q * 8;

    floatx4 acc1[9], acc3[2];
#pragma unroll
    for (int n = 0; n < 9; ++n) { acc1[n][0]=0.f; acc1[n][1]=0.f; acc1[n][2]=0.f; acc1[n][3]=0.f; }
#pragma unroll
    for (int n = 0; n < 2; ++n) { acc3[n][0]=0.f; acc3[n][1]=0.f; acc3[n][2]=0.f; acc3[n][3]=0.f; }

    const int base = blockIdx.x & 15;   // K-phase rotation (channel spread)

    // frag source address for (K-chunk kn, slot sl):
    //   slots 0..8  = W1P[kn][0..8]
    //   slots 9,10  = WCP[kn*2 + {0,1}]        (cf half)
    //   slots 11,12 = WCP[(16+kn)*2 + {0,1}]   (nf half)
    auto fsrc = [&](int kn, int sl) -> const unsigned short* {
        if (sl < 9)  return W1P + (size_t)(kn * 9 + sl) * 512 + lo8;
        if (sl < 11) return WCP + (size_t)(kn * 2 + (sl - 9)) * 512 + lo8;
        return WCP + (size_t)((16 + kn) * 2 + (sl - 11)) * 512 + lo8;
    };

    // ---- main loop: 16 sections, single-buffer LDS frag staging (2-barrier)
    {
        const int sl0 = w, sl1 = w + 4, sl2 = w + 8;   // wave w stages these
        bf16x8 r0, r1, r2, r3;
        // prologue: frag(0) -> regs, stream s(0) -> set A
        r0 = *(const bf16x8*)fsrc(base, sl0);
        r1 = *(const bf16x8*)fsrc(base, sl1);
        r2 = *(const bf16x8*)fsrc(base, sl2);
        r3 = r0;
        if (w == 0) r3 = *(const bf16x8*)fsrc(base, 12);
        float4 ax0, ax1, ay0, ay1, bx0, bx1, by0, by1;
        ax0 = *(const float4*)(cfr + base * 32);
        ax1 = *(const float4*)(cfr + base * 32 + 4);
        ay0 = *(const float4*)(nfr + base * 32);
        ay1 = *(const float4*)(nfr + base * 32 + 4);
        bx0 = ax0; bx1 = ax1; by0 = ay0; by1 = ay1;

#pragma unroll
        for (int i = 0; i < 16; ++i) {
            // ds_write section-i frags (regs loaded last section / prologue)
            {
                unsigned short* fd = fragbuf + lo8;
                *(bf16x8*)(fd + sl0 * 512) = r0;
                *(bf16x8*)(fd + sl1 * 512) = r1;
                *(bf16x8*)(fd + sl2 * 512) = r2;
                if (w == 0) *(bf16x8*)(fd + 12 * 512) = r3;
            }
            // stage loads for section i+1 (in flight until the barrier)
            if (i < 15) {
                const int kn = (base + i + 1) & 15;
                r0 = *(const bf16x8*)fsrc(kn, sl0);
                r1 = *(const bf16x8*)fsrc(kn, sl1);
                r2 = *(const bf16x8*)fsrc(kn, sl2);
                if (w == 0) r3 = *(const bf16x8*)fsrc(kn, 12);
                if ((i & 1) == 0) {
                    bx0 = *(const float4*)(cfr + kn * 32);
                    bx1 = *(const float4*)(cfr + kn * 32 + 4);
                    by0 = *(const float4*)(nfr + kn * 32);
                    by1 = *(const float4*)(nfr + kn * 32 + 4);
                } else {
                    ax0 = *(const float4*)(cfr + kn * 32);
                    ax1 = *(const float4*)(cfr + kn * 32 + 4);
                    ay0 = *(const float4*)(nfr + kn * 32);
                    ay1 = *(const float4*)(nfr + kn * 32 + 4);
                }
            }
            __syncthreads();   // frag writes visible to all waves

            // compute section i: 13 ds_read_b128 + 13 MFMA
            {
                const unsigned short* fs = fragbuf + lo8;
                float4 cx0 = ((i & 1) == 0) ? ax0 : bx0;
                float4 cx1 = ((i & 1) == 0) ? ax1 : bx1;
                float4 cy0 = ((i & 1) == 0) ? ay0 : by0;
                float4 cy1 = ((i & 1) == 0) ? ay1 : by1;
                bf16x8 avc = cvt8r(cx0, cx1);
                bf16x8 avn = cvt8r(cy0, cy1);
                bf16x8 f0 = *(const bf16x8*)(fs + 0 * 512);
                bf16x8 f1 = *(const bf16x8*)(fs + 1 * 512);
                bf16x8 f2 = *(const bf16x8*)(fs + 2 * 512);
                bf16x8 f3 = *(const bf16x8*)(fs + 3 * 512);
                bf16x8 f4 = *(const bf16x8*)(fs + 4 * 512);
                bf16x8 f5 = *(const bf16x8*)(fs + 5 * 512);
                bf16x8 f6 = *(const bf16x8*)(fs + 6 * 512);
                bf16x8 f7 = *(const bf16x8*)(fs + 7 * 512);
                bf16x8 f8 = *(const bf16x8*)(fs + 8 * 512);
                bf16x8 c0 = *(const bf16x8*)(fs + 9 * 512);
                bf16x8 c1 = *(const bf16x8*)(fs + 10 * 512);
                bf16x8 c2 = *(const bf16x8*)(fs + 11 * 512);
                bf16x8 c3 = *(const bf16x8*)(fs + 12 * 512);
                acc1[0] = MFMA16(avc, f0, acc1[0]);
                acc1[1] = MFMA16(avc, f1, acc1[1]);
                acc1[2] = MFMA16(avc, f2, acc1[2]);
                acc1[3] = MFMA16(avc, f3, acc1[3]);
                acc1[4] = MFMA16(avc, f4, acc1[4]);
                acc1[5] = MFMA16(avc, f5, acc1[5]);
                acc1[6] = MFMA16(avc, f6, acc1[6]);
                acc1[7] = MFMA16(avc, f7, acc1[7]);
                acc1[8] = MFMA16(avc, f8, acc1[8]);
                acc3[0] = MFMA16(avc, c0, acc3[0]);
                acc3[1] = MFMA16(avc, c1, acc3[1]);
                acc3[0] = MFMA16(avn, c2, acc3[0]);
                acc3[1] = MFMA16(avn, c3, acc3[1]);
            }
            __syncthreads();   // all readers done before next section's writes
        }
    }

    // ---- epilogue 1: h = acc1 + b1 + one-hot rows; write bf16 to LDS (hs)
    // C/D layout: col = lane&15, row = quad*4 + i.  hs stride 168 shorts.
    const int r0w = w * 16 + (q << 2);
#pragma unroll
    for (int i = 0; i < 4; ++i) {
        int rr = r0w + i;
        int s0 = sidx[rr * 3], s1 = sidx[rr * 3 + 1], s2 = sidx[rr * 3 + 2];
#pragma unroll
        for (int n = 0; n < 9; ++n) {
            int j = n * 16 + col;
            float v = acc1[n][i] + b1s[j] + Us[s0 * 144 + j] + Us[s1 * 144 + j] + Us[s2 * 144 + j];
            fragbuf[rr * 168 + j] = f2bf(v);
        }
    }
    {   // zero pad cols 144..159 (phase-2 K reads zeros there)
        int rr = t >> 2, g = t & 3;
        ushort4 z; z.x = z.y = z.z = z.w = 0;
        *(ushort4*)(fragbuf + rr * 168 + 144 + g * 4) = z;
    }
    // inv logits -> LDS (frees acc3 before phase 2)
#pragma unroll
    for (int n = 0; n < 2; ++n) {
        int j = n * 16 + col;
        if (j < 18) {
#pragma unroll
            for (int i = 0; i < 4; ++i) Ls[(r0w + i) * 20 + j] = acc3[n][i];
        }
    }
    __syncthreads();

    // ---- phase 2: pred = h @ W2 + b2 (K=160, 5 chunks), split into 2 halves
    // of 8 n-tiles to halve accumulator registers (32 vs 64 AGPR peak)
    {
        const unsigned short* hsp = fragbuf;
#pragma unroll 1
        for (int half = 0; half < 2; ++half) {
            floatx4 acc2[8];
#pragma unroll
            for (int n = 0; n < 8; ++n) { acc2[n][0]=0.f; acc2[n][1]=0.f; acc2[n][2]=0.f; acc2[n][3]=0.f; }
            for (int kc = 0; kc < 5; ++kc) {
                bf16x8 av = *(const bf16x8*)(hsp + (w * 16 + col) * 168 + kc * 32 + q * 8);
                const unsigned short* bp = W2P + (size_t)(kc * 16 + half * 8) * 512 + lo8;
#pragma unroll
                for (int n = 0; n < 8; ++n)
                    acc2[n] = MFMA16(av, *(const bf16x8*)(bp + n * 512), acc2[n]);
            }
#pragma unroll
            for (int n = 0; n < 8; ++n) {
                int j = (half * 8 + n) * 16 + col;
                float bj = b2s[j];
#pragma unroll
                for (int i = 0; i < 4; ++i)
                    outp[(size_t)(m0 + r0w + i) * 256 + j] = acc2[n][i] + bj;
            }
        }
    }

    // ---- phase 3: softmax over 32 agents per frame
    if (t < 36) {
        int fr = t / 18, j = t - fr * 18;
        float mx = -1e30f;
        for (int a = 0; a < 32; ++a) mx = fmaxf(mx, Ls[(fr * 32 + a) * 20 + j]);
        float s = 0.f;
        for (int a = 0; a < 32; ++a) s += expf(Ls[(fr * 32 + a) * 20 + j] - mx);
        rmx[t] = mx; rsc[t] = 1.f / s;
    }
    __syncthreads();

#pragma unroll
    for (int it = 0; it < 5; ++it) {               // 64*18 = 1152 outputs
        int idx = t + it * 256;
        if (idx < 1152) {
            int r = idx / 18, j = idx - r * 18;
            int fr = r >> 5;
            float v = expf(Ls[r * 20 + j] - rmx[fr * 18 + j]) * rsc[fr * 18 + j];
            int m = m0 + r;
            size_t o;
            if (j < 8)       o = OFF_A0 + (size_t)m * 8 + j;
            else if (j < 14) o = OFF_A1 + (size_t)m * 6 + (j - 8);
            else             o = OFF_A2 + (size_t)m * 4 + (j - 14);
            outp[o] = v;
        }
    }
}

// ---------------------------------------------------------------------------
extern "C" void kernel_launch(void* const* d_in, const int* in_sizes, int n_in,
                              void* d_out, int out_size, void* d_ws, size_t ws_size,
                              hipStream_t stream)
{
    const float* cf  = (const float*)d_in[0];
    const float* nf  = (const float*)d_in[1];
    const int*   act = (const int*)d_in[2];
    const float* W1  = (const float*)d_in[3];
    const float* b1  = (const float*)d_in[4];
    const float* W2  = (const float*)d_in[5];
    const float* b2  = (const float*)d_in[6];
    const float* Wi0 = (const float*)d_in[7];
    const float* Wi1 = (const float*)d_in[9];
    const float* Wi2 = (const float*)d_in[11];

    unsigned short* ws = (unsigned short*)d_ws;
    float* outp = (float*)d_out;

    hipLaunchKernelGGL(prep_kernel, dim3(144), dim3(256), 0, stream,
                       W1, W2, Wi0, Wi1, Wi2, ws);
    hipLaunchKernelGGL(fused_kernel, dim3(1024), dim3(256), 0, stream,
                       cf, nf, act, W1, b1, b2, ws, outp);
}

// Round 9
// 339.073 us; speedup vs baseline: 1.0405x; 1.0127x over previous
//
#include <hip/hip_runtime.h>

// ---------------------------------------------------------------------------
// AdversarialHead, fully fused single-pass kernel.
//
//   h[m,140]    = cf[m,:] @ W1[0:512,:] + W1[512+s0] + W1[512+s1] + W1[512+s2] + b1
//   pred[m,256] = h[m,:] @ W2 + b2
//   L[m,18]     = cf[m,:] @ Wc[0:512,:] + nf[m,:] @ Wc[512:1024,:]  (bias=0)
//   a*(f,a,j)   = softmax over a (32 agents/frame);  m = f*32+a, M = 65536
//
// Round-9b (round-8's nontemporal attempt, compile-fixed): the builtin
// rejects HIP_vector_type<float,4>; streams now use clang ext-vector
// floatx4 ([] indexing) which the builtin accepts. Theory unchanged:
// counters show work/instruction accounting is exact, all pipes <11% busy,
// perf INSENSITIVE to occupancy/pipeline depth (rounds 2/4/6/8) -> fixed
// per-CU memory-path limiter. Stream loads are 16-line gathers at 2KB
// stride (same L1 set), ~64B used per line: they thrash L1 sets and exhaust
// per-CU miss slots, capping in-flight bytes at ~2.3KB/CU (measured).
//  * Stream loads -> __builtin_nontemporal_load (zero reuse; bypass L1 path).
//  * Output stores -> __builtin_nontemporal_store (no read-back).
//  * Weight frags stay cached (real L1/L2 reuse). Everything else identical
//    to round-8 for a clean single-variable A/B.
// ---------------------------------------------------------------------------

using bf16x8  = __attribute__((ext_vector_type(8))) __bf16;
using floatx4 = __attribute__((ext_vector_type(4))) float;

__device__ __forceinline__ unsigned short f2bf(float f) {
    unsigned int u = __float_as_uint(f);
    return (unsigned short)((u + 0x7fffu + ((u >> 16) & 1u)) >> 16);
}
__device__ __forceinline__ bf16x8 cvt8r(floatx4 x, floatx4 y) {
    union { bf16x8 v; unsigned short s[8]; } u;
    u.s[0] = f2bf(x[0]); u.s[1] = f2bf(x[1]); u.s[2] = f2bf(x[2]); u.s[3] = f2bf(x[3]);
    u.s[4] = f2bf(y[0]); u.s[5] = f2bf(y[1]); u.s[6] = f2bf(y[2]); u.s[7] = f2bf(y[3]);
    return u.v;
}

__device__ __forceinline__ floatx4 ntl4(const float* p) {
    return __builtin_nontemporal_load(reinterpret_cast<const floatx4*>(p));
}

// prepacked ws offsets (bf16 elements)
#define OFF_W1P 0                        // [16][9][64][8]   gemm1 B-frags
#define OFF_W2P (OFF_W1P + 16*9*512)     // [5][16][64][8]   gemm2 B-frags
#define OFF_WCP (OFF_W2P + 5*16*512)     // [32][2][64][8]   inv   B-frags

// d_out element offsets (fp32)
#define OFF_A0 ((size_t)16777216)
#define OFF_A1 ((size_t)17301504)
#define OFF_A2 ((size_t)17694720)

// ---------------------------------------------------------------------------
// Prepack weights fp32 -> bf16 in B-fragment order.
// frag elem: lane l holds B[n*16 + (l&15)][kc*32 + (l>>4)*8 + e], e=0..7.
__global__ __launch_bounds__(256) void prep_kernel(
    const float* __restrict__ W1,   // [530][140]
    const float* __restrict__ W2,   // [140][256]
    const float* __restrict__ Wi0,  // [1024][8]
    const float* __restrict__ Wi1,  // [1024][6]
    const float* __restrict__ Wi2,  // [1024][4]
    unsigned short* __restrict__ ws)
{
    const int T1 = 16*9*512;           // 73728
    const int T2 = T1 + 5*16*512;      // 114688
    const int total = T2 + 32*2*512;   // 147456
    for (int idx = blockIdx.x * 256 + threadIdx.x; idx < total; idx += gridDim.x * 256) {
        unsigned short v = 0;
        if (idx < T1) {                               // W1P
            int e = idx & 7, l = (idx >> 3) & 63;
            int n = (idx >> 9) % 9, kc = idx / (9*512);
            int k = kc*32 + ((l >> 4) << 3) + e, j = n*16 + (l & 15);
            if (j < 140) v = f2bf(W1[k*140 + j]);
            ws[OFF_W1P + idx] = v;
        } else if (idx < T2) {                        // W2P (K padded 140->160)
            int i2 = idx - T1;
            int e = i2 & 7, l = (i2 >> 3) & 63;
            int n = (i2 >> 9) & 15, kc = i2 >> 13;
            int k = kc*32 + ((l >> 4) << 3) + e, j = n*16 + (l & 15);
            if (k < 140) v = f2bf(W2[k*256 + j]);
            ws[OFF_W2P + i2] = v;
        } else {                                      // WcP: heads concat (8|6|4)
            int i3 = idx - T2;
            int e = i3 & 7, l = (i3 >> 3) & 63;
            int n = (i3 >> 9) & 1, kc = i3 >> 10;
            int k = kc*32 + ((l >> 4) << 3) + e, j = n*16 + (l & 15);
            if (j < 8)       v = f2bf(Wi0[k*8 + j]);
            else if (j < 14) v = f2bf(Wi1[k*6 + (j - 8)]);
            else if (j < 18) v = f2bf(Wi2[k*4 + (j - 14)]);
            ws[OFF_WCP + i3] = v;
        }
    }
}

#define MFMA16(av, bv, acc) __builtin_amdgcn_mfma_f32_16x16x32_bf16(av, bv, acc, 0, 0, 0)

// ---------------------------------------------------------------------------
__global__ __launch_bounds__(256) void fused_kernel(
    const float* __restrict__ cf,
    const float* __restrict__ nf,
    const int* __restrict__ actions,   // [2048][3][32]
    const float* __restrict__ W1,      // rows 512..529: one-hot add rows
    const float* __restrict__ b1,
    const float* __restrict__ b2,
    const unsigned short* __restrict__ ws,
    float* __restrict__ outp)
{
    // frag staging (13 slots x 1024 B = 13312 B) UNION hs (64x168x2 = 21504 B)
    __shared__ alignas(16) unsigned short fragbuf[64 * 168];
    __shared__ float Us[18 * 144];                // one-hot rows of W1 (fp32)
    __shared__ float b1s[144];
    __shared__ float b2s[256];
    __shared__ float Ls[64 * 20];                 // inv logits
    __shared__ float rmx[36], rsc[36];
    __shared__ int   sidx[192];

    const int t = threadIdx.x, w = t >> 6, l = t & 63;
    const int m0 = blockIdx.x * 64;
    const int q = l >> 4, col = l & 15;
    const int lo8 = l * 8;
    const unsigned short* W1P = ws + OFF_W1P;
    const unsigned short* W2P = ws + OFF_W2P;
    const unsigned short* WCP = ws + OFF_WCP;

    // ---- stage constants: hoist loads into regs (all in flight), then LDS
    {
        float uv[11];
#pragma unroll
        for (int it = 0; it < 11; ++it) {
            int i = t + it * 256;
            uv[it] = 0.f;
            if (i < 18 * 144) {
                int s = i / 144, j = i - s * 144;
                if (j < 140) uv[it] = W1[(512 + s) * 140 + j];
            }
        }
        float bv1 = (t < 140) ? b1[t] : 0.f;
        float bv2 = b2[t];
        int sv = 0;
        if (t < 192) {
            int r = t / 3, tt = t - r * 3;
            int m = m0 + r;
            int start = (tt == 0) ? 0 : (tt == 1 ? 8 : 14);
            sv = actions[(m >> 5) * 96 + tt * 32 + (m & 31)] + start;
        }
#pragma unroll
        for (int it = 0; it < 11; ++it) {
            int i = t + it * 256;
            if (i < 18 * 144) Us[i] = uv[it];
        }
        if (t < 144) b1s[t] = bv1;
        b2s[t] = bv2;
        if (t < 192) sidx[t] = sv;
    }

    // A-frag source row for this lane (A layout: row = lane&15, k = quad*8+j)
    const float* cfr = cf + (size_t)(m0 + w * 16 + col) * 512 + q * 8;
    const float* nfr = nf + (size_t)(m0 + w * 16 + col) * 512 + q * 8;

    floatx4 acc1[9], acc3[2];
#pragma unroll
    for (int n = 0; n < 9; ++n) { acc1[n][0]=0.f; acc1[n][1]=0.f; acc1[n][2]=0.f; acc1[n][3]=0.f; }
#pragma unroll
    for (int n = 0; n < 2; ++n) { acc3[n][0]=0.f; acc3[n][1]=0.f; acc3[n][2]=0.f; acc3[n][3]=0.f; }

    const int base = blockIdx.x & 15;   // K-phase rotation (channel spread)

    // frag source address for (K-chunk kn, slot sl):
    //   slots 0..8  = W1P[kn][0..8]
    //   slots 9,10  = WCP[kn*2 + {0,1}]        (cf half)
    //   slots 11,12 = WCP[(16+kn)*2 + {0,1}]   (nf half)
    auto fsrc = [&](int kn, int sl) -> const unsigned short* {
        if (sl < 9)  return W1P + (size_t)(kn * 9 + sl) * 512 + lo8;
        if (sl < 11) return WCP + (size_t)(kn * 2 + (sl - 9)) * 512 + lo8;
        return WCP + (size_t)((16 + kn) * 2 + (sl - 11)) * 512 + lo8;
    };

    // ---- main loop: 16 sections, single-buffer LDS frag staging (2-barrier)
    {
        const int sl0 = w, sl1 = w + 4, sl2 = w + 8;   // wave w stages these
        bf16x8 r0, r1, r2, r3;
        // prologue: frag(0) -> regs, stream s(0) -> set A
        r0 = *(const bf16x8*)fsrc(base, sl0);
        r1 = *(const bf16x8*)fsrc(base, sl1);
        r2 = *(const bf16x8*)fsrc(base, sl2);
        r3 = r0;
        if (w == 0) r3 = *(const bf16x8*)fsrc(base, 12);
        floatx4 ax0, ax1, ay0, ay1, bx0, bx1, by0, by1;
        ax0 = ntl4(cfr + base * 32);
        ax1 = ntl4(cfr + base * 32 + 4);
        ay0 = ntl4(nfr + base * 32);
        ay1 = ntl4(nfr + base * 32 + 4);
        bx0 = ax0; bx1 = ax1; by0 = ay0; by1 = ay1;

#pragma unroll
        for (int i = 0; i < 16; ++i) {
            // ds_write section-i frags (regs loaded last section / prologue)
            {
                unsigned short* fd = fragbuf + lo8;
                *(bf16x8*)(fd + sl0 * 512) = r0;
                *(bf16x8*)(fd + sl1 * 512) = r1;
                *(bf16x8*)(fd + sl2 * 512) = r2;
                if (w == 0) *(bf16x8*)(fd + 12 * 512) = r3;
            }
            // stage loads for section i+1 (in flight until the barrier)
            if (i < 15) {
                const int kn = (base + i + 1) & 15;
                r0 = *(const bf16x8*)fsrc(kn, sl0);
                r1 = *(const bf16x8*)fsrc(kn, sl1);
                r2 = *(const bf16x8*)fsrc(kn, sl2);
                if (w == 0) r3 = *(const bf16x8*)fsrc(kn, 12);
                if ((i & 1) == 0) {
                    bx0 = ntl4(cfr + kn * 32);
                    bx1 = ntl4(cfr + kn * 32 + 4);
                    by0 = ntl4(nfr + kn * 32);
                    by1 = ntl4(nfr + kn * 32 + 4);
                } else {
                    ax0 = ntl4(cfr + kn * 32);
                    ax1 = ntl4(cfr + kn * 32 + 4);
                    ay0 = ntl4(nfr + kn * 32);
                    ay1 = ntl4(nfr + kn * 32 + 4);
                }
            }
            __syncthreads();   // frag writes visible to all waves

            // compute section i: 13 ds_read_b128 + 13 MFMA
            {
                const unsigned short* fs = fragbuf + lo8;
                floatx4 cx0 = ((i & 1) == 0) ? ax0 : bx0;
                floatx4 cx1 = ((i & 1) == 0) ? ax1 : bx1;
                floatx4 cy0 = ((i & 1) == 0) ? ay0 : by0;
                floatx4 cy1 = ((i & 1) == 0) ? ay1 : by1;
                bf16x8 avc = cvt8r(cx0, cx1);
                bf16x8 avn = cvt8r(cy0, cy1);
                bf16x8 f0 = *(const bf16x8*)(fs + 0 * 512);
                bf16x8 f1 = *(const bf16x8*)(fs + 1 * 512);
                bf16x8 f2 = *(const bf16x8*)(fs + 2 * 512);
                bf16x8 f3 = *(const bf16x8*)(fs + 3 * 512);
                bf16x8 f4 = *(const bf16x8*)(fs + 4 * 512);
                bf16x8 f5 = *(const bf16x8*)(fs + 5 * 512);
                bf16x8 f6 = *(const bf16x8*)(fs + 6 * 512);
                bf16x8 f7 = *(const bf16x8*)(fs + 7 * 512);
                bf16x8 f8 = *(const bf16x8*)(fs + 8 * 512);
                bf16x8 c0 = *(const bf16x8*)(fs + 9 * 512);
                bf16x8 c1 = *(const bf16x8*)(fs + 10 * 512);
                bf16x8 c2 = *(const bf16x8*)(fs + 11 * 512);
                bf16x8 c3 = *(const bf16x8*)(fs + 12 * 512);
                acc1[0] = MFMA16(avc, f0, acc1[0]);
                acc1[1] = MFMA16(avc, f1, acc1[1]);
                acc1[2] = MFMA16(avc, f2, acc1[2]);
                acc1[3] = MFMA16(avc, f3, acc1[3]);
                acc1[4] = MFMA16(avc, f4, acc1[4]);
                acc1[5] = MFMA16(avc, f5, acc1[5]);
                acc1[6] = MFMA16(avc, f6, acc1[6]);
                acc1[7] = MFMA16(avc, f7, acc1[7]);
                acc1[8] = MFMA16(avc, f8, acc1[8]);
                acc3[0] = MFMA16(avc, c0, acc3[0]);
                acc3[1] = MFMA16(avc, c1, acc3[1]);
                acc3[0] = MFMA16(avn, c2, acc3[0]);
                acc3[1] = MFMA16(avn, c3, acc3[1]);
            }
            __syncthreads();   // all readers done before next section's writes
        }
    }

    // ---- epilogue 1: h = acc1 + b1 + one-hot rows; write bf16 to LDS (hs)
    // C/D layout: col = lane&15, row = quad*4 + i.  hs stride 168 shorts.
    const int r0w = w * 16 + (q << 2);
#pragma unroll
    for (int i = 0; i < 4; ++i) {
        int rr = r0w + i;
        int s0 = sidx[rr * 3], s1 = sidx[rr * 3 + 1], s2 = sidx[rr * 3 + 2];
#pragma unroll
        for (int n = 0; n < 9; ++n) {
            int j = n * 16 + col;
            float v = acc1[n][i] + b1s[j] + Us[s0 * 144 + j] + Us[s1 * 144 + j] + Us[s2 * 144 + j];
            fragbuf[rr * 168 + j] = f2bf(v);
        }
    }
    {   // zero pad cols 144..159 (phase-2 K reads zeros there)
        int rr = t >> 2, g = t & 3;
        ushort4 z; z.x = z.y = z.z = z.w = 0;
        *(ushort4*)(fragbuf + rr * 168 + 144 + g * 4) = z;
    }
    // inv logits -> LDS (frees acc3 before phase 2)
#pragma unroll
    for (int n = 0; n < 2; ++n) {
        int j = n * 16 + col;
        if (j < 18) {
#pragma unroll
            for (int i = 0; i < 4; ++i) Ls[(r0w + i) * 20 + j] = acc3[n][i];
        }
    }
    __syncthreads();

    // ---- phase 2: pred = h @ W2 + b2 (K=160, 5 chunks), split into 2 halves
    // of 8 n-tiles to halve accumulator registers (32 vs 64 AGPR peak)
    {
        const unsigned short* hsp = fragbuf;
#pragma unroll 1
        for (int half = 0; half < 2; ++half) {
            floatx4 acc2[8];
#pragma unroll
            for (int n = 0; n < 8; ++n) { acc2[n][0]=0.f; acc2[n][1]=0.f; acc2[n][2]=0.f; acc2[n][3]=0.f; }
            for (int kc = 0; kc < 5; ++kc) {
                bf16x8 av = *(const bf16x8*)(hsp + (w * 16 + col) * 168 + kc * 32 + q * 8);
                const unsigned short* bp = W2P + (size_t)(kc * 16 + half * 8) * 512 + lo8;
#pragma unroll
                for (int n = 0; n < 8; ++n)
                    acc2[n] = MFMA16(av, *(const bf16x8*)(bp + n * 512), acc2[n]);
            }
#pragma unroll
            for (int n = 0; n < 8; ++n) {
                int j = (half * 8 + n) * 16 + col;
                float bj = b2s[j];
#pragma unroll
                for (int i = 0; i < 4; ++i)
                    __builtin_nontemporal_store(acc2[n][i] + bj,
                        &outp[(size_t)(m0 + r0w + i) * 256 + j]);
            }
        }
    }

    // ---- phase 3: softmax over 32 agents per frame
    if (t < 36) {
        int fr = t / 18, j = t - fr * 18;
        float mx = -1e30f;
        for (int a = 0; a < 32; ++a) mx = fmaxf(mx, Ls[(fr * 32 + a) * 20 + j]);
        float s = 0.f;
        for (int a = 0; a < 32; ++a) s += expf(Ls[(fr * 32 + a) * 20 + j] - mx);
        rmx[t] = mx; rsc[t] = 1.f / s;
    }
    __syncthreads();

#pragma unroll
    for (int it = 0; it < 5; ++it) {               // 64*18 = 1152 outputs
        int idx = t + it * 256;
        if (idx < 1152) {
            int r = idx / 18, j = idx - r * 18;
            int fr = r >> 5;
            float v = expf(Ls[r * 20 + j] - rmx[fr * 18 + j]) * rsc[fr * 18 + j];
            int m = m0 + r;
            size_t o;
            if (j < 8)       o = OFF_A0 + (size_t)m * 8 + j;
            else if (j < 14) o = OFF_A1 + (size_t)m * 6 + (j - 8);
            else             o = OFF_A2 + (size_t)m * 4 + (j - 14);
            __builtin_nontemporal_store(v, &outp[o]);
        }
    }
}

// ---------------------------------------------------------------------------
extern "C" void kernel_launch(void* const* d_in, const int* in_sizes, int n_in,
                              void* d_out, int out_size, void* d_ws, size_t ws_size,
                              hipStream_t stream)
{
    const float* cf  = (const float*)d_in[0];
    const float* nf  = (const float*)d_in[1];
    const int*   act = (const int*)d_in[2];
    const float* W1  = (const float*)d_in[3];
    const float* b1  = (const float*)d_in[4];
    const float* W2  = (const float*)d_in[5];
    const float* b2  = (const float*)d_in[6];
    const float* Wi0 = (const float*)d_in[7];
    const float* Wi1 = (const float*)d_in[9];
    const float* Wi2 = (const float*)d_in[11];

    unsigned short* ws = (unsigned short*)d_ws;
    float* outp = (float*)d_out;

    hipLaunchKernelGGL(prep_kernel, dim3(144), dim3(256), 0, stream,
                       W1, W2, Wi0, Wi1, Wi2, ws);
    hipLaunchKernelGGL(fused_kernel, dim3(1024), dim3(256), 0, stream,
                       cf, nf, act, W1, b1, b2, ws, outp);
}